// Round 2
// baseline (7471.169 us; speedup 1.0000x reference)
//
#include <hip/hip_runtime.h>
#include <hip/hip_bf16.h>

typedef __bf16 bf16_t;
typedef __bf16 bf16x8_t __attribute__((ext_vector_type(8)));
typedef __bf16 bf16x4_t __attribute__((ext_vector_type(4)));
typedef float  f32x4_t  __attribute__((ext_vector_type(4)));

#define N1_ROWS 100000
#define N2_ROWS 25000
#define DIN  128
#define DHID 256
#define DOUT 64

// ---------------- weight transpose + cast: W[K][N] f32 -> WT[N][K] bf16 ----------------
__global__ __launch_bounds__(256) void transpose_w(
    const float* __restrict__ W, bf16_t* __restrict__ WT, int K, int N) {
  int gid = blockIdx.x * 256 + threadIdx.x;
  if (gid >= K * N) return;
  int n = gid / K, k = gid - n * K;
  WT[gid] = (bf16_t)W[k * N + n];
}

// ---------------- fused dual GEMM: out = act(A1@W1 + A2@W2 + b) ----------------
// A row-major MxK (f32 if AF32 else bf16), WT n-major NxK bf16 (pre-transposed),
// N == BN (block covers full output width).
// MFMA 16x16x32 bf16. A-frag: m=lane&15, k=quad*8+j. B-frag: n=lane&15, k=quad*8+j.
// C/D: col=lane&15, row=quad*4+reg.
template<int BN, bool RELU, bool OUTF32, bool AF32>
__global__ __launch_bounds__(256) void gemm_dual(
    const void* __restrict__ A1v, const void* __restrict__ A2v,
    const bf16_t* __restrict__ W1T, const bf16_t* __restrict__ W2T,
    const float* __restrict__ bias, void* __restrict__ outp,
    int M, int K1, int K2) {
  constexpr int BM = 64, BK = 32;
  __shared__ bf16_t sA[BM * BK];
  __shared__ bf16_t sB[BN * BK];
  const int tid  = threadIdx.x;
  const int wave = tid >> 6, lane = tid & 63;
  const int l15  = lane & 15, quad = lane >> 4;
  const int rowBase = blockIdx.x * BM;

  f32x4_t acc[BN / 16];
#pragma unroll
  for (int t = 0; t < BN / 16; ++t) acc[t] = (f32x4_t){0.f, 0.f, 0.f, 0.f};

  const int ldr = tid >> 2;        // 0..63 (row within tile)
  const int ldk = (tid & 3) * 8;   // 0,8,16,24 (k offset, 8 elems/thread)

  for (int half = 0; half < 2; ++half) {
    const void* A  = half ? A2v : A1v;
    const bf16_t* WT = half ? W2T : W1T;
    const int K = half ? K2 : K1;
    for (int k0 = 0; k0 < K; k0 += BK) {
      __syncthreads();
      {
        int gr = rowBase + ldr; if (gr >= M) gr = M - 1;  // clamp (stores guarded)
        if (AF32) {
          const float* Af = (const float*)A;
          float4 lo = *(const float4*)&Af[(size_t)gr * K + k0 + ldk];
          float4 hi = *(const float4*)&Af[(size_t)gr * K + k0 + ldk + 4];
          bf16x8_t v;
          v[0] = (bf16_t)lo.x; v[1] = (bf16_t)lo.y; v[2] = (bf16_t)lo.z; v[3] = (bf16_t)lo.w;
          v[4] = (bf16_t)hi.x; v[5] = (bf16_t)hi.y; v[6] = (bf16_t)hi.z; v[7] = (bf16_t)hi.w;
          *(bf16x8_t*)&sA[ldr * BK + ldk] = v;
        } else {
          const bf16_t* Ab = (const bf16_t*)A;
          *(uint4*)&sA[ldr * BK + ldk] = *(const uint4*)&Ab[(size_t)gr * K + k0 + ldk];
        }
      }
#pragma unroll
      for (int p = 0; p < BN / 64; ++p) {
        int r = p * 64 + ldr;
        *(uint4*)&sB[r * BK + ldk] = *(const uint4*)&WT[(size_t)r * K + k0 + ldk];
      }
      __syncthreads();
      bf16x8_t a = *(const bf16x8_t*)&sA[(wave * 16 + l15) * BK + quad * 8];
#pragma unroll
      for (int t = 0; t < BN / 16; ++t) {
        bf16x8_t b = *(const bf16x8_t*)&sB[(t * 16 + l15) * BK + quad * 8];
        acc[t] = __builtin_amdgcn_mfma_f32_16x16x32_bf16(a, b, acc[t], 0, 0, 0);
      }
    }
  }

  const int rbase = rowBase + wave * 16 + quad * 4;
#pragma unroll
  for (int t = 0; t < BN / 16; ++t) {
    int col = t * 16 + l15;
    float bv = bias[col];
#pragma unroll
    for (int i = 0; i < 4; ++i) {
      int row = rbase + i;
      if (row < M) {
        float v = acc[t][i] + bv;
        if (RELU) v = fmaxf(v, 0.f);
        if (OUTF32) ((float*)outp)[(size_t)row * BN + col] = v;
        else        ((bf16_t*)outp)[(size_t)row * BN + col] = (bf16_t)v;
      }
    }
  }
}

// ---------------- scatter-add (segment sum) over edges: 64 lanes = 256 ch / edge ----------------
__global__ __launch_bounds__(256) void scatter_add(
    const bf16_t* __restrict__ X, const int* __restrict__ src,
    const int* __restrict__ dst, float* __restrict__ accum,
    float* __restrict__ cnt, int E) {
  long long gid = (long long)blockIdx.x * 256 + threadIdx.x;
  int e = (int)(gid >> 6);
  if (e >= E) return;
  int lane = (int)(gid & 63);
  int s = src[e], d = dst[e];
  bf16x4_t v = *(const bf16x4_t*)(X + (size_t)s * DHID + lane * 4);
  float* ap = accum + (size_t)d * DHID + lane * 4;
  atomicAdd(ap + 0, (float)v[0]);
  atomicAdd(ap + 1, (float)v[1]);
  atomicAdd(ap + 2, (float)v[2]);
  atomicAdd(ap + 3, (float)v[3]);
  if (lane == 0) atomicAdd(cnt + d, 1.0f);
}

// ---------------- mean + cast to bf16 ----------------
__global__ __launch_bounds__(256) void finalize_mean(
    const float* __restrict__ accum, const float* __restrict__ cnt,
    bf16_t* __restrict__ outp, int n) {
  int gid = blockIdx.x * 256 + threadIdx.x;
  int idx = gid * 4;
  if (idx >= n * DHID) return;
  int d = idx >> 8;
  float c = fmaxf(cnt[d], 1.0f);
  float4 v = *(const float4*)(accum + idx);
  bf16x4_t o;
  o[0] = (bf16_t)(v.x / c); o[1] = (bf16_t)(v.y / c);
  o[2] = (bf16_t)(v.z / c); o[3] = (bf16_t)(v.w / c);
  *(bf16x4_t*)(outp + idx) = o;
}

// ---------------- log_softmax over 64 cols, one wave per row, in-place f32 ----------------
__global__ __launch_bounds__(256) void log_softmax64(
    float* __restrict__ logits, int R) {
  int gid = blockIdx.x * 256 + threadIdx.x;
  int row = gid >> 6, lane = gid & 63;
  if (row >= R) return;
  float v = logits[(size_t)row * DOUT + lane];
  float m = v;
  for (int o = 32; o > 0; o >>= 1) m = fmaxf(m, __shfl_xor(m, o, 64));
  float e = expf(v - m);
  float s = e;
  for (int o = 32; o > 0; o >>= 1) s += __shfl_xor(s, o, 64);
  logits[(size_t)row * DOUT + lane] = v - m - logf(s);
}

extern "C" void kernel_launch(void* const* d_in, const int* in_sizes, int n_in,
                              void* d_out, int out_size, void* d_ws, size_t ws_size,
                              hipStream_t stream) {
  const float* x_tar   = (const float*)d_in[0];
  const float* x_neigh = (const float*)d_in[1];
  const int* es0 = (const int*)d_in[2];
  const int* ed0 = (const int*)d_in[3];
  const int* es1 = (const int*)d_in[4];
  const int* ed1 = (const int*)d_in[5];
  // d_in[6], d_in[7]: n_dst0 / n_dst1 scalars (fixed: 100000 / 25000)
  const float* Wl0 = (const float*)d_in[8];
  const float* Wr0 = (const float*)d_in[9];
  const float* b0  = (const float*)d_in[10];
  const float* Wl1 = (const float*)d_in[11];
  const float* Wr1 = (const float*)d_in[12];
  const float* b1  = (const float*)d_in[13];
  const float* Wl2 = (const float*)d_in[14];
  const float* Wr2 = (const float*)d_in[15];
  const float* b2  = (const float*)d_in[16];

  const int E0 = in_sizes[2];
  const int E1 = in_sizes[4];
  const int M0 = in_sizes[0] / DIN;  // 400000

  // -------- workspace layout (~359.4 MB) --------
  char* ws = (char*)d_ws;
  bf16_t* Wl0T = (bf16_t*)(ws + 0);        // 256x128 bf16 -> 64KB
  bf16_t* Wr0T = (bf16_t*)(ws + 65536);
  bf16_t* Wl1T = (bf16_t*)(ws + 131072);   // 256x256 -> 128KB
  bf16_t* Wr1T = (bf16_t*)(ws + 262144);
  bf16_t* Wl2T = (bf16_t*)(ws + 393216);   // 64x256 -> 32KB
  bf16_t* Wr2T = (bf16_t*)(ws + 425984);
  bf16_t* x0   = (bf16_t*)(ws + 524288);                 // 400000x256 bf16 = 204.8MB
  char*   regB = ws + 524288 + 204800000;                // 102.4MB multi-use region
  float*  aggrF  = (float*)regB;                         // 100000x256 f32 (layer-0 accum)
  bf16_t* x1     = (bf16_t*)regB;                        // reuse: 100000x256 bf16
  float*  aggr2F = (float*)(regB + 51200000);            // 25000x256 f32
  bf16_t* aggr2B = (bf16_t*)(regB + 76800000);           // 25000x256 bf16
  float*  cnt1   = (float*)(regB + 96000000);            // 25000 f32
  bf16_t* aggrB  = (bf16_t*)(ws + 307724288);            // 100000x256 bf16 = 51.2MB
  float*  cnt0   = (float*)(ws + 358924288);             // 100000 f32
  float*  logits = (float*)d_out;                        // 25000x64 f32, softmax in-place

  // 1. pre-transpose weights into n-major bf16 (MFMA B-fragment friendly)
  transpose_w<<<(DIN * DHID + 255) / 256, 256, 0, stream>>>(Wl0, Wl0T, DIN, DHID);
  transpose_w<<<(DIN * DHID + 255) / 256, 256, 0, stream>>>(Wr0, Wr0T, DIN, DHID);
  transpose_w<<<(DHID * DHID + 255) / 256, 256, 0, stream>>>(Wl1, Wl1T, DHID, DHID);
  transpose_w<<<(DHID * DHID + 255) / 256, 256, 0, stream>>>(Wr1, Wr1T, DHID, DHID);
  transpose_w<<<(DHID * DOUT + 255) / 256, 256, 0, stream>>>(Wl2, Wl2T, DHID, DOUT);
  transpose_w<<<(DHID * DOUT + 255) / 256, 256, 0, stream>>>(Wr2, Wr2T, DHID, DOUT);

  // 2. zero layer-0 accumulators (ws is re-poisoned 0xAA before every call)
  hipMemsetAsync(aggrF, 0, (size_t)N1_ROWS * DHID * 4, stream);
  hipMemsetAsync(cnt0, 0, (size_t)N1_ROWS * 4, stream);

  // 3. x0 = x_neigh@Wl0 + x_tar@Wr0 + b0  (f32 in, bf16 out)
  gemm_dual<DHID, false, false, true><<<(M0 + 63) / 64, 256, 0, stream>>>(
      x_neigh, x_tar, Wl0T, Wr0T, b0, x0, M0, DIN, DIN);

  // 4-5. segment mean over edges0
  scatter_add<<<(int)(((long long)E0 * 64 + 255) / 256), 256, 0, stream>>>(
      x0, es0, ed0, aggrF, cnt0, E0);
  finalize_mean<<<(N1_ROWS * DHID / 4 + 255) / 256, 256, 0, stream>>>(
      aggrF, cnt0, aggrB, N1_ROWS);

  // 6. x1 = relu(aggr@Wl1 + x0[:N1]@Wr1 + b1)   (x1 overwrites dead aggrF)
  gemm_dual<DHID, true, false, false><<<(N1_ROWS + 63) / 64, 256, 0, stream>>>(
      aggrB, x0, Wl1T, Wr1T, b1, x1, N1_ROWS, DHID, DHID);

  // 7. zero layer-1 accumulators
  hipMemsetAsync(aggr2F, 0, (size_t)N2_ROWS * DHID * 4, stream);
  hipMemsetAsync(cnt1, 0, (size_t)N2_ROWS * 4, stream);

  // 8-9. segment mean over edges1
  scatter_add<<<(int)(((long long)E1 * 64 + 255) / 256), 256, 0, stream>>>(
      x1, es1, ed1, aggr2F, cnt1, E1);
  finalize_mean<<<(N2_ROWS * DHID / 4 + 255) / 256, 256, 0, stream>>>(
      aggr2F, cnt1, aggr2B, N2_ROWS);

  // 10. logits = aggr2@Wl2 + x1[:N2]@Wr2 + b2  (f32 out, straight into d_out)
  gemm_dual<DOUT, false, true, false><<<(N2_ROWS + 63) / 64, 256, 0, stream>>>(
      aggr2B, x1, Wl2T, Wr2T, b2, logits, N2_ROWS, DHID, DHID);

  // 11. log_softmax in-place on d_out
  log_softmax64<<<(int)(((long long)N2_ROWS * 64 + 255) / 256), 256, 0, stream>>>(
      logits, N2_ROWS);
}

// Round 3
// 1101.230 us; speedup vs baseline: 6.7844x; 6.7844x over previous
//
#include <hip/hip_runtime.h>
#include <hip/hip_bf16.h>

typedef __bf16 bf16_t;
typedef __bf16 bf16x8_t __attribute__((ext_vector_type(8)));
typedef __bf16 bf16x4_t __attribute__((ext_vector_type(4)));
typedef float  f32x4_t  __attribute__((ext_vector_type(4)));

#define N1_ROWS 100000
#define N2_ROWS 25000
#define DIN  128
#define DHID 256
#define DOUT 64
#define CAP  96   // max bucket slots per dst; Poisson(16) => P(deg>=96) ~ 1e-50

// ---------------- weight transpose + cast: W[K][N] f32 -> WT[N][K] bf16 ----------------
__global__ __launch_bounds__(256) void transpose_w(
    const float* __restrict__ W, bf16_t* __restrict__ WT, int K, int N) {
  int gid = blockIdx.x * 256 + threadIdx.x;
  if (gid >= K * N) return;
  int n = gid / K, k = gid - n * K;
  WT[gid] = (bf16_t)W[k * N + n];
}

// ---------------- fused dual GEMM: out = act(A1@W1 + A2@W2 + b) ----------------
// A row-major MxK (f32 if AF32 else bf16), WT n-major NxK bf16 (pre-transposed),
// N == BN (block covers full output width).
// MFMA 16x16x32 bf16. A-frag: m=lane&15, k=quad*8+j. B-frag: n=lane&15, k=quad*8+j.
// C/D: col=lane&15, row=quad*4+reg.
template<int BN, bool RELU, bool OUTF32, bool AF32>
__global__ __launch_bounds__(256) void gemm_dual(
    const void* __restrict__ A1v, const void* __restrict__ A2v,
    const bf16_t* __restrict__ W1T, const bf16_t* __restrict__ W2T,
    const float* __restrict__ bias, void* __restrict__ outp,
    int M, int K1, int K2) {
  constexpr int BM = 64, BK = 32;
  __shared__ bf16_t sA[BM * BK];
  __shared__ bf16_t sB[BN * BK];
  const int tid  = threadIdx.x;
  const int wave = tid >> 6, lane = tid & 63;
  const int l15  = lane & 15, quad = lane >> 4;
  const int rowBase = blockIdx.x * BM;

  f32x4_t acc[BN / 16];
#pragma unroll
  for (int t = 0; t < BN / 16; ++t) acc[t] = (f32x4_t){0.f, 0.f, 0.f, 0.f};

  const int ldr = tid >> 2;        // 0..63 (row within tile)
  const int ldk = (tid & 3) * 8;   // 0,8,16,24 (k offset, 8 elems/thread)

  for (int half = 0; half < 2; ++half) {
    const void* A  = half ? A2v : A1v;
    const bf16_t* WT = half ? W2T : W1T;
    const int K = half ? K2 : K1;
    for (int k0 = 0; k0 < K; k0 += BK) {
      __syncthreads();
      {
        int gr = rowBase + ldr; if (gr >= M) gr = M - 1;  // clamp (stores guarded)
        if (AF32) {
          const float* Af = (const float*)A;
          float4 lo = *(const float4*)&Af[(size_t)gr * K + k0 + ldk];
          float4 hi = *(const float4*)&Af[(size_t)gr * K + k0 + ldk + 4];
          bf16x8_t v;
          v[0] = (bf16_t)lo.x; v[1] = (bf16_t)lo.y; v[2] = (bf16_t)lo.z; v[3] = (bf16_t)lo.w;
          v[4] = (bf16_t)hi.x; v[5] = (bf16_t)hi.y; v[6] = (bf16_t)hi.z; v[7] = (bf16_t)hi.w;
          *(bf16x8_t*)&sA[ldr * BK + ldk] = v;
        } else {
          const bf16_t* Ab = (const bf16_t*)A;
          *(uint4*)&sA[ldr * BK + ldk] = *(const uint4*)&Ab[(size_t)gr * K + k0 + ldk];
        }
      }
#pragma unroll
      for (int p = 0; p < BN / 64; ++p) {
        int r = p * 64 + ldr;
        *(uint4*)&sB[r * BK + ldk] = *(const uint4*)&WT[(size_t)r * K + k0 + ldk];
      }
      __syncthreads();
      bf16x8_t a = *(const bf16x8_t*)&sA[(wave * 16 + l15) * BK + quad * 8];
#pragma unroll
      for (int t = 0; t < BN / 16; ++t) {
        bf16x8_t b = *(const bf16x8_t*)&sB[(t * 16 + l15) * BK + quad * 8];
        acc[t] = __builtin_amdgcn_mfma_f32_16x16x32_bf16(a, b, acc[t], 0, 0, 0);
      }
    }
  }

  const int rbase = rowBase + wave * 16 + quad * 4;
#pragma unroll
  for (int t = 0; t < BN / 16; ++t) {
    int col = t * 16 + l15;
    float bv = bias[col];
#pragma unroll
    for (int i = 0; i < 4; ++i) {
      int row = rbase + i;
      if (row < M) {
        float v = acc[t][i] + bv;
        if (RELU) v = fmaxf(v, 0.f);
        if (OUTF32) ((float*)outp)[(size_t)row * BN + col] = v;
        else        ((bf16_t*)outp)[(size_t)row * BN + col] = (bf16_t)v;
      }
    }
  }
}

// ---------------- build padded reverse index: bucket[dst][i] = src ----------------
__global__ __launch_bounds__(256) void csr_append(
    const int* __restrict__ src, const int* __restrict__ dst,
    int* __restrict__ cnt, int* __restrict__ csr, int E) {
  int e = blockIdx.x * 256 + threadIdx.x;
  if (e >= E) return;
  int d = dst[e];
  int pos = atomicAdd(&cnt[d], 1);
  if (pos < CAP) csr[(size_t)d * CAP + pos] = src[e];
}

// ---------------- pull-mode segment mean: one wave per dst node ----------------
__global__ __launch_bounds__(256) void gather_mean(
    const bf16_t* __restrict__ X, const int* __restrict__ csr,
    const int* __restrict__ cnt, bf16_t* __restrict__ outp, int n) {
  int gid = blockIdx.x * 256 + threadIdx.x;
  int d = gid >> 6, lane = gid & 63;
  if (d >= n) return;
  int deg = cnt[d]; if (deg > CAP) deg = CAP;
  const int* bucket = csr + (size_t)d * CAP;
  float a0 = 0.f, a1 = 0.f, a2 = 0.f, a3 = 0.f;
  for (int i = 0; i < deg; ++i) {
    int s = bucket[i];
    bf16x4_t v = *(const bf16x4_t*)(X + (size_t)s * DHID + lane * 4);
    a0 += (float)v[0]; a1 += (float)v[1]; a2 += (float)v[2]; a3 += (float)v[3];
  }
  float inv = 1.f / (float)(deg > 0 ? deg : 1);
  bf16x4_t o;
  o[0] = (bf16_t)(a0 * inv); o[1] = (bf16_t)(a1 * inv);
  o[2] = (bf16_t)(a2 * inv); o[3] = (bf16_t)(a3 * inv);
  *(bf16x4_t*)(outp + (size_t)d * DHID + lane * 4) = o;
}

// ---------------- log_softmax over 64 cols, one wave per row, in-place f32 ----------------
__global__ __launch_bounds__(256) void log_softmax64(
    float* __restrict__ logits, int R) {
  int gid = blockIdx.x * 256 + threadIdx.x;
  int row = gid >> 6, lane = gid & 63;
  if (row >= R) return;
  float v = logits[(size_t)row * DOUT + lane];
  float m = v;
  for (int o = 32; o > 0; o >>= 1) m = fmaxf(m, __shfl_xor(m, o, 64));
  float e = expf(v - m);
  float s = e;
  for (int o = 32; o > 0; o >>= 1) s += __shfl_xor(s, o, 64);
  logits[(size_t)row * DOUT + lane] = v - m - logf(s);
}

extern "C" void kernel_launch(void* const* d_in, const int* in_sizes, int n_in,
                              void* d_out, int out_size, void* d_ws, size_t ws_size,
                              hipStream_t stream) {
  const float* x_tar   = (const float*)d_in[0];
  const float* x_neigh = (const float*)d_in[1];
  const int* es0 = (const int*)d_in[2];
  const int* ed0 = (const int*)d_in[3];
  const int* es1 = (const int*)d_in[4];
  const int* ed1 = (const int*)d_in[5];
  // d_in[6], d_in[7]: n_dst0 / n_dst1 scalars (fixed: 100000 / 25000)
  const float* Wl0 = (const float*)d_in[8];
  const float* Wr0 = (const float*)d_in[9];
  const float* b0  = (const float*)d_in[10];
  const float* Wl1 = (const float*)d_in[11];
  const float* Wr1 = (const float*)d_in[12];
  const float* b1  = (const float*)d_in[13];
  const float* Wl2 = (const float*)d_in[14];
  const float* Wr2 = (const float*)d_in[15];
  const float* b2  = (const float*)d_in[16];

  const int E0 = in_sizes[2];
  const int E1 = in_sizes[4];
  const int M0 = in_sizes[0] / DIN;  // 400000

  // -------- workspace layout (~318 MB) --------
  char* ws = (char*)d_ws;
  bf16_t* Wl0T = (bf16_t*)(ws + 0);        // 256x128 bf16 -> 64KB
  bf16_t* Wr0T = (bf16_t*)(ws + 65536);
  bf16_t* Wl1T = (bf16_t*)(ws + 131072);   // 256x256 -> 128KB
  bf16_t* Wr1T = (bf16_t*)(ws + 262144);
  bf16_t* Wl2T = (bf16_t*)(ws + 393216);   // 64x256 -> 32KB
  bf16_t* Wr2T = (bf16_t*)(ws + 425984);
  bf16_t* x0     = (bf16_t*)(ws + 524288);               // 400000x256 bf16 = 204.8MB
  bf16_t* x1     = (bf16_t*)(ws + 524288 + 51200000);    // aliases x0 rows [100000,200000) (dead)
  bf16_t* aggrB  = (bf16_t*)(ws + 205324288);            // 100000x256 bf16 = 51.2MB
  bf16_t* aggr2B = (bf16_t*)(ws + 256524288);            // 25000x256 bf16 = 12.8MB
  int*    csr0   = (int*)(ws + 269324288);               // 100000x96 int = 38.4MB
  int*    csr1   = (int*)(ws + 307724288);               // 25000x96 int = 9.6MB
  int*    cnt0   = (int*)(ws + 317324288);               // 400KB
  int*    cnt1   = (int*)(ws + 317724288);               // 100KB
  float*  logits = (float*)d_out;                        // 25000x64 f32, softmax in-place

  // 1. pre-transpose weights into n-major bf16 (MFMA B-fragment friendly)
  transpose_w<<<(DIN * DHID + 255) / 256, 256, 0, stream>>>(Wl0, Wl0T, DIN, DHID);
  transpose_w<<<(DIN * DHID + 255) / 256, 256, 0, stream>>>(Wr0, Wr0T, DIN, DHID);
  transpose_w<<<(DHID * DHID + 255) / 256, 256, 0, stream>>>(Wl1, Wl1T, DHID, DHID);
  transpose_w<<<(DHID * DHID + 255) / 256, 256, 0, stream>>>(Wr1, Wr1T, DHID, DHID);
  transpose_w<<<(DHID * DOUT + 255) / 256, 256, 0, stream>>>(Wl2, Wl2T, DHID, DOUT);
  transpose_w<<<(DHID * DOUT + 255) / 256, 256, 0, stream>>>(Wr2, Wr2T, DHID, DOUT);

  // 2. zero bucket counters (ws re-poisoned 0xAA before every call)
  hipMemsetAsync(cnt0, 0, (size_t)N1_ROWS * 4, stream);
  hipMemsetAsync(cnt1, 0, (size_t)N2_ROWS * 4, stream);

  // 3. build reverse index for edges0 (independent of gemm0)
  csr_append<<<(E0 + 255) / 256, 256, 0, stream>>>(es0, ed0, cnt0, csr0, E0);

  // 4. x0 = x_neigh@Wl0 + x_tar@Wr0 + b0  (f32 in, bf16 out)
  gemm_dual<DHID, false, false, true><<<(M0 + 63) / 64, 256, 0, stream>>>(
      x_neigh, x_tar, Wl0T, Wr0T, b0, x0, M0, DIN, DIN);

  // 5. segment mean over edges0 (pull, register accumulation)
  gather_mean<<<(int)(((long long)N1_ROWS * 64 + 255) / 256), 256, 0, stream>>>(
      x0, csr0, cnt0, aggrB, N1_ROWS);

  // 6. x1 = relu(aggr@Wl1 + x0[:N1]@Wr1 + b1)
  gemm_dual<DHID, true, false, false><<<(N1_ROWS + 63) / 64, 256, 0, stream>>>(
      aggrB, x0, Wl1T, Wr1T, b1, x1, N1_ROWS, DHID, DHID);

  // 7. build reverse index for edges1
  csr_append<<<(E1 + 255) / 256, 256, 0, stream>>>(es1, ed1, cnt1, csr1, E1);

  // 8. segment mean over edges1
  gather_mean<<<(int)(((long long)N2_ROWS * 64 + 255) / 256), 256, 0, stream>>>(
      x1, csr1, cnt1, aggr2B, N2_ROWS);

  // 9. logits = aggr2@Wl2 + x1[:N2]@Wr2 + b2  (f32 out, straight into d_out)
  gemm_dual<DOUT, false, true, false><<<(N2_ROWS + 63) / 64, 256, 0, stream>>>(
      aggr2B, x1, Wl2T, Wr2T, b2, logits, N2_ROWS, DHID, DHID);

  // 10. log_softmax in-place on d_out
  log_softmax64<<<(int)(((long long)N2_ROWS * 64 + 255) / 256), 256, 0, stream>>>(
      logits, N2_ROWS);
}

// Round 4
// 953.231 us; speedup vs baseline: 7.8377x; 1.1553x over previous
//
#include <hip/hip_runtime.h>
#include <hip/hip_bf16.h>

typedef __bf16 bf16_t;
typedef __bf16 bf16x8_t __attribute__((ext_vector_type(8)));
typedef __bf16 bf16x4_t __attribute__((ext_vector_type(4)));
typedef float  f32x4_t  __attribute__((ext_vector_type(4)));

#define N1_ROWS 100000
#define N2_ROWS 25000
#define DIN  128
#define DHID 256
#define DOUT 64
#define CAP  96   // max bucket slots per dst; Poisson(16) => P(deg>=96) ~ 1e-50

// ---------------- all 6 weight transposes in one launch ----------------
// W[K][N] f32 -> WT[N][K] bf16
__global__ __launch_bounds__(256) void prep_weights(
    const float* __restrict__ Wl0, const float* __restrict__ Wr0,
    const float* __restrict__ Wl1, const float* __restrict__ Wr1,
    const float* __restrict__ Wl2, const float* __restrict__ Wr2,
    bf16_t* __restrict__ Wl0T, bf16_t* __restrict__ Wr0T,
    bf16_t* __restrict__ Wl1T, bf16_t* __restrict__ Wr1T,
    bf16_t* __restrict__ Wl2T, bf16_t* __restrict__ Wr2T) {
  int b = blockIdx.x;
  const float* W; bf16_t* WT; int K, N, base;
  if      (b < 128) { W = Wl0; WT = Wl0T; K = 128; N = 256; base = 0;   }
  else if (b < 256) { W = Wr0; WT = Wr0T; K = 128; N = 256; base = 128; }
  else if (b < 512) { W = Wl1; WT = Wl1T; K = 256; N = 256; base = 256; }
  else if (b < 768) { W = Wr1; WT = Wr1T; K = 256; N = 256; base = 512; }
  else if (b < 832) { W = Wl2; WT = Wl2T; K = 256; N = 64;  base = 768; }
  else              { W = Wr2; WT = Wr2T; K = 256; N = 64;  base = 832; }
  int gid = (b - base) * 256 + threadIdx.x;
  int n = gid / K, k = gid - n * K;
  WT[gid] = (bf16_t)W[(size_t)k * N + n];
}

// ---------------- fused dual GEMM, m97-shaped ----------------
// Block: 64 rows x (NT*64) cols, 4 waves, wave tile 64 x (NT*16).
// A row-major MxK staged through padded LDS (f32->bf16 fused if AF32);
// B fragments read DIRECT from global WT (n-major NxK bf16, L2-resident).
// MFMA 16x16x32: A-frag m=l15,k=quad*8+j; B-frag n=l15; C/D col=l15,row=quad*4+reg.
template<int NT, bool RELU, bool OUTF32, bool AF32>
__global__ __launch_bounds__(256) void gemm_fast(
    const void* __restrict__ A1v, const void* __restrict__ A2v,
    const bf16_t* __restrict__ W1T, const bf16_t* __restrict__ W2T,
    const float* __restrict__ bias, void* __restrict__ outp,
    int M, int K1, int K2) {
  constexpr int BK = 32;
  constexpr int LDA = 40;                 // 32 + 8 pad -> stride 80B: <=2-way banks
  __shared__ bf16_t sA[64 * LDA];
  const int tid  = threadIdx.x;
  const int wave = tid >> 6, lane = tid & 63;
  const int l15  = lane & 15, quad = lane >> 4;
  const int rowBase = blockIdx.x * 64;
  const int colBase = wave * (NT * 16);
  constexpr int NOUT = NT * 64;           // output row stride

  f32x4_t acc[4][NT];
#pragma unroll
  for (int mt = 0; mt < 4; ++mt)
#pragma unroll
    for (int nt = 0; nt < NT; ++nt) acc[mt][nt] = (f32x4_t){0.f, 0.f, 0.f, 0.f};

  const int sr = tid >> 2;        // 0..63  (A stage row)
  const int sc = (tid & 3) * 8;   // 0,8,16,24 (A stage k-offset, 8 elems)
  int gr = rowBase + sr; if (gr >= M) gr = M - 1;   // clamp; stores guarded

  for (int half = 0; half < 2; ++half) {
    const void* A = half ? A2v : A1v;
    const bf16_t* WT = half ? W2T : W1T;
    const int K = half ? K2 : K1;
    for (int k0 = 0; k0 < K; k0 += BK) {
      // B fragments straight from global (weights stay L2-hot) — issue early
      bf16x8_t bf[NT];
#pragma unroll
      for (int nt = 0; nt < NT; ++nt)
        bf[nt] = *(const bf16x8_t*)&WT[(size_t)(colBase + nt * 16 + l15) * K + k0 + quad * 8];
      __syncthreads();
      if (AF32) {
        const float* Af = (const float*)A;
        float4 lo = *(const float4*)&Af[(size_t)gr * K + k0 + sc];
        float4 hi = *(const float4*)&Af[(size_t)gr * K + k0 + sc + 4];
        bf16x8_t v;
        v[0] = (bf16_t)lo.x; v[1] = (bf16_t)lo.y; v[2] = (bf16_t)lo.z; v[3] = (bf16_t)lo.w;
        v[4] = (bf16_t)hi.x; v[5] = (bf16_t)hi.y; v[6] = (bf16_t)hi.z; v[7] = (bf16_t)hi.w;
        *(bf16x8_t*)&sA[sr * LDA + sc] = v;
      } else {
        *(uint4*)&sA[sr * LDA + sc] =
            *(const uint4*)&((const bf16_t*)A)[(size_t)gr * K + k0 + sc];
      }
      __syncthreads();
#pragma unroll
      for (int mt = 0; mt < 4; ++mt) {
        bf16x8_t af = *(const bf16x8_t*)&sA[(mt * 16 + l15) * LDA + quad * 8];
#pragma unroll
        for (int nt = 0; nt < NT; ++nt)
          acc[mt][nt] = __builtin_amdgcn_mfma_f32_16x16x32_bf16(af, bf[nt], acc[mt][nt], 0, 0, 0);
      }
    }
  }

  const int rb = rowBase + quad * 4;
#pragma unroll
  for (int mt = 0; mt < 4; ++mt)
#pragma unroll
    for (int nt = 0; nt < NT; ++nt) {
      int col = colBase + nt * 16 + l15;
      float bv = bias[col];
#pragma unroll
      for (int i = 0; i < 4; ++i) {
        int row = rb + mt * 16 + i;
        if (row < M) {
          float v = acc[mt][nt][i] + bv;
          if (RELU) v = fmaxf(v, 0.f);
          if (OUTF32) ((float*)outp)[(size_t)row * NOUT + col] = v;
          else        ((bf16_t*)outp)[(size_t)row * NOUT + col] = (bf16_t)v;
        }
      }
    }
}

// ---------------- both reverse-index builds in one launch ----------------
__global__ __launch_bounds__(256) void csr_append2(
    const int* __restrict__ s0, const int* __restrict__ d0, int E0,
    int* __restrict__ cnt0, int* __restrict__ csr0,
    const int* __restrict__ s1, const int* __restrict__ d1, int E1,
    int* __restrict__ cnt1, int* __restrict__ csr1, int B0) {
  int b = blockIdx.x;
  if (b < B0) {
    int e = b * 256 + threadIdx.x;
    if (e < E0) {
      int d = d0[e];
      int pos = atomicAdd(&cnt0[d], 1);
      if (pos < CAP) csr0[(size_t)d * CAP + pos] = s0[e];
    }
  } else {
    int e = (b - B0) * 256 + threadIdx.x;
    if (e < E1) {
      int d = d1[e];
      int pos = atomicAdd(&cnt1[d], 1);
      if (pos < CAP) csr1[(size_t)d * CAP + pos] = s1[e];
    }
  }
}

// ---------------- pull-mode segment mean: one wave per dst, 4x unrolled ----------------
__global__ __launch_bounds__(256) void gather_mean(
    const bf16_t* __restrict__ X, const int* __restrict__ csr,
    const int* __restrict__ cnt, bf16_t* __restrict__ outp, int n) {
  int gid = blockIdx.x * 256 + threadIdx.x;
  int d = gid >> 6, lane = gid & 63;
  if (d >= n) return;
  int deg = cnt[d]; if (deg > CAP) deg = CAP;
  const int* bucket = csr + (size_t)d * CAP;
  f32x4_t A0 = {0,0,0,0}, A1 = {0,0,0,0}, A2 = {0,0,0,0}, A3 = {0,0,0,0};
  int i = 0;
  for (; i + 4 <= deg; i += 4) {
    int s0 = bucket[i], s1 = bucket[i+1], s2 = bucket[i+2], s3 = bucket[i+3];
    bf16x4_t v0 = *(const bf16x4_t*)(X + (size_t)s0 * DHID + lane * 4);
    bf16x4_t v1 = *(const bf16x4_t*)(X + (size_t)s1 * DHID + lane * 4);
    bf16x4_t v2 = *(const bf16x4_t*)(X + (size_t)s2 * DHID + lane * 4);
    bf16x4_t v3 = *(const bf16x4_t*)(X + (size_t)s3 * DHID + lane * 4);
#pragma unroll
    for (int j = 0; j < 4; ++j) {
      A0[j] += (float)v0[j]; A1[j] += (float)v1[j];
      A2[j] += (float)v2[j]; A3[j] += (float)v3[j];
    }
  }
  for (; i < deg; ++i) {
    int s = bucket[i];
    bf16x4_t v = *(const bf16x4_t*)(X + (size_t)s * DHID + lane * 4);
#pragma unroll
    for (int j = 0; j < 4; ++j) A0[j] += (float)v[j];
  }
  float inv = 1.f / (float)(deg > 0 ? deg : 1);
  bf16x4_t o;
#pragma unroll
  for (int j = 0; j < 4; ++j)
    o[j] = (bf16_t)((A0[j] + A1[j] + A2[j] + A3[j]) * inv);
  *(bf16x4_t*)(outp + (size_t)d * DHID + lane * 4) = o;
}

// ---------------- log_softmax over 64 cols, one wave per row, in-place f32 ----------------
__global__ __launch_bounds__(256) void log_softmax64(
    float* __restrict__ logits, int R) {
  int gid = blockIdx.x * 256 + threadIdx.x;
  int row = gid >> 6, lane = gid & 63;
  if (row >= R) return;
  float v = logits[(size_t)row * DOUT + lane];
  float m = v;
  for (int o = 32; o > 0; o >>= 1) m = fmaxf(m, __shfl_xor(m, o, 64));
  float e = expf(v - m);
  float s = e;
  for (int o = 32; o > 0; o >>= 1) s += __shfl_xor(s, o, 64);
  logits[(size_t)row * DOUT + lane] = v - m - logf(s);
}

extern "C" void kernel_launch(void* const* d_in, const int* in_sizes, int n_in,
                              void* d_out, int out_size, void* d_ws, size_t ws_size,
                              hipStream_t stream) {
  const float* x_tar   = (const float*)d_in[0];
  const float* x_neigh = (const float*)d_in[1];
  const int* es0 = (const int*)d_in[2];
  const int* ed0 = (const int*)d_in[3];
  const int* es1 = (const int*)d_in[4];
  const int* ed1 = (const int*)d_in[5];
  // d_in[6], d_in[7]: n_dst0 / n_dst1 scalars (fixed: 100000 / 25000)
  const float* Wl0 = (const float*)d_in[8];
  const float* Wr0 = (const float*)d_in[9];
  const float* b0  = (const float*)d_in[10];
  const float* Wl1 = (const float*)d_in[11];
  const float* Wr1 = (const float*)d_in[12];
  const float* b1  = (const float*)d_in[13];
  const float* Wl2 = (const float*)d_in[14];
  const float* Wr2 = (const float*)d_in[15];
  const float* b2  = (const float*)d_in[16];

  const int E0 = in_sizes[2];
  const int E1 = in_sizes[4];
  const int M0 = in_sizes[0] / DIN;  // 400000

  // -------- workspace layout (~318 MB) --------
  char* ws = (char*)d_ws;
  bf16_t* Wl0T = (bf16_t*)(ws + 0);        // 256n x 128k bf16 -> 64KB
  bf16_t* Wr0T = (bf16_t*)(ws + 65536);
  bf16_t* Wl1T = (bf16_t*)(ws + 131072);   // 256x256 -> 128KB
  bf16_t* Wr1T = (bf16_t*)(ws + 262144);
  bf16_t* Wl2T = (bf16_t*)(ws + 393216);   // 64x256 -> 32KB
  bf16_t* Wr2T = (bf16_t*)(ws + 425984);
  bf16_t* x0     = (bf16_t*)(ws + 524288);               // 400000x256 bf16 = 204.8MB
  bf16_t* x1     = (bf16_t*)(ws + 524288 + 51200000);    // aliases x0 rows [100000,200000) (dead)
  bf16_t* aggrB  = (bf16_t*)(ws + 205324288);            // 100000x256 bf16
  bf16_t* aggr2B = (bf16_t*)(ws + 256524288);            // 25000x256 bf16
  int*    csr0   = (int*)(ws + 269324288);               // 100000x96 int
  int*    csr1   = (int*)(ws + 307724288);               // 25000x96 int
  int*    cnt0   = (int*)(ws + 317324288);               // 400KB
  int*    cnt1   = (int*)(ws + 317724288);               // 100KB (adjacent to cnt0)
  float*  logits = (float*)d_out;                        // 25000x64 f32, softmax in-place

  // 1. all weight transposes, one launch
  prep_weights<<<896, 256, 0, stream>>>(Wl0, Wr0, Wl1, Wr1, Wl2, Wr2,
                                        Wl0T, Wr0T, Wl1T, Wr1T, Wl2T, Wr2T);

  // 2. zero both bucket counters in one memset (ws re-poisoned before every call)
  hipMemsetAsync(cnt0, 0, (size_t)(N1_ROWS + N2_ROWS) * 4, stream);

  // 3. both reverse indexes, one launch
  {
    int B0 = (E0 + 255) / 256, B1 = (E1 + 255) / 256;
    csr_append2<<<B0 + B1, 256, 0, stream>>>(es0, ed0, E0, cnt0, csr0,
                                             es1, ed1, E1, cnt1, csr1, B0);
  }

  // 4. x0 = x_neigh@Wl0 + x_tar@Wr0 + b0  (f32 in, bf16 out)
  gemm_fast<4, false, false, true><<<(M0 + 63) / 64, 256, 0, stream>>>(
      x_neigh, x_tar, Wl0T, Wr0T, b0, x0, M0, DIN, DIN);

  // 5. segment mean over edges0 (pull, register accumulation)
  gather_mean<<<(int)(((long long)N1_ROWS * 64 + 255) / 256), 256, 0, stream>>>(
      x0, csr0, cnt0, aggrB, N1_ROWS);

  // 6. x1 = relu(aggr@Wl1 + x0[:N1]@Wr1 + b1)
  gemm_fast<4, true, false, false><<<(N1_ROWS + 63) / 64, 256, 0, stream>>>(
      aggrB, x0, Wl1T, Wr1T, b1, x1, N1_ROWS, DHID, DHID);

  // 7. segment mean over edges1
  gather_mean<<<(int)(((long long)N2_ROWS * 64 + 255) / 256), 256, 0, stream>>>(
      x1, csr1, cnt1, aggr2B, N2_ROWS);

  // 8. logits = aggr2@Wl2 + x1[:N2]@Wr2 + b2  (f32 out, straight into d_out)
  gemm_fast<1, false, true, false><<<(N2_ROWS + 63) / 64, 256, 0, stream>>>(
      aggr2B, x1, Wl2T, Wr2T, b2, logits, N2_ROWS, DHID, DHID);

  // 9. log_softmax in-place on d_out
  log_softmax64<<<(int)(((long long)N2_ROWS * 64 + 255) / 256), 256, 0, stream>>>(
      logits, N2_ROWS);
}